// Round 1
// baseline (1051.220 us; speedup 1.0000x reference)
//
#include <hip/hip_runtime.h>

#define K_DIM 25088   // 512*49
#define N_DIM 1000
#define M_DIM 256

// ---------------------------------------------------------------------------
// Kernel 1: split-K partial GEMM. C_part[z, m, n] = sum_{k in chunk z} A[m,k]*W[n,k]
// A: inputR (256 x 25088) row-major, W: weight (1000 x 25088) row-major.
// 128x128 tile, BK=16, 8x8 micro-tile per thread, transposed LDS for b128 reads.
// ---------------------------------------------------------------------------
__global__ __launch_bounds__(256) void gemm_partial_k(
    const float* __restrict__ A, const float* __restrict__ W,
    float* __restrict__ part, int kchunk) {
  __shared__ float As_t[16][132];  // [kk][m], +4 pad keeps rows 16B-aligned
  __shared__ float Ws_t[16][132];  // [kk][n]
  const int t  = threadIdx.x;
  const int m0 = blockIdx.x * 128;           // M=256 -> 2 tiles
  const int n0 = blockIdx.y * 128;           // N=1000 -> 8 tiles (pad to 1024)
  const int kz = blockIdx.z;
  const int k0 = kz * kchunk;
  const int tx8 = (t & 15) << 3;
  const int ty8 = (t >> 4) << 3;

  float acc[8][8];
#pragma unroll
  for (int i = 0; i < 8; ++i)
#pragma unroll
    for (int j = 0; j < 8; ++j) acc[i][j] = 0.f;

  for (int k = k0; k < k0 + kchunk; k += 16) {
    // stage: 128 rows x 16 k-cols for both operands, float4 loads, transpose into LDS
#pragma unroll
    for (int h = 0; h < 2; ++h) {
      const int q    = t + h * 256;     // 0..511
      const int row  = q >> 2;          // 0..127
      const int col4 = (q & 3) << 2;    // 0,4,8,12
      float4 av = *(const float4*)(A + (size_t)(m0 + row) * K_DIM + k + col4);
      As_t[col4 + 0][row] = av.x;
      As_t[col4 + 1][row] = av.y;
      As_t[col4 + 2][row] = av.z;
      As_t[col4 + 3][row] = av.w;
      const int wr = n0 + row;
      float4 wv = make_float4(0.f, 0.f, 0.f, 0.f);
      if (wr < N_DIM) wv = *(const float4*)(W + (size_t)wr * K_DIM + k + col4);
      Ws_t[col4 + 0][row] = wv.x;
      Ws_t[col4 + 1][row] = wv.y;
      Ws_t[col4 + 2][row] = wv.z;
      Ws_t[col4 + 3][row] = wv.w;
    }
    __syncthreads();
#pragma unroll
    for (int kk = 0; kk < 16; ++kk) {
      float a8[8], b8[8];
      *(float4*)&a8[0] = *(const float4*)&As_t[kk][ty8];
      *(float4*)&a8[4] = *(const float4*)&As_t[kk][ty8 + 4];
      *(float4*)&b8[0] = *(const float4*)&Ws_t[kk][tx8];
      *(float4*)&b8[4] = *(const float4*)&Ws_t[kk][tx8 + 4];
#pragma unroll
      for (int i = 0; i < 8; ++i)
#pragma unroll
        for (int j = 0; j < 8; ++j)
          acc[i][j] = fmaf(a8[i], b8[j], acc[i][j]);
    }
    __syncthreads();
  }

  // store partial tile (N padded to 1024 in workspace)
  float* pbase = part + ((size_t)kz * 256 + m0) * 1024 + n0;
#pragma unroll
  for (int i = 0; i < 8; ++i) {
    float* prow = pbase + (size_t)(ty8 + i) * 1024 + tx8;
    *(float4*)(prow)     = make_float4(acc[i][0], acc[i][1], acc[i][2], acc[i][3]);
    *(float4*)(prow + 4) = make_float4(acc[i][4], acc[i][5], acc[i][6], acc[i][7]);
  }
}

// ---------------------------------------------------------------------------
// Kernel 2: reduce split-K partials + bias -> outputR (first 256000 floats of out)
// ---------------------------------------------------------------------------
__global__ __launch_bounds__(256) void reduce_bias_k(
    const float* __restrict__ part, const float* __restrict__ bias,
    float* __restrict__ outR, int splitk) {
  const int id = blockIdx.x * 256 + threadIdx.x;
  if (id >= M_DIM * N_DIM) return;
  const int n = id / N_DIM;
  const int o = id - n * N_DIM;
  float s = 0.f;
  for (int z = 0; z < splitk; ++z)
    s += part[((size_t)z * 256 + n) * 1024 + o];
  outR[id] = s + bias[o];
}

// ---------------------------------------------------------------------------
// Kernel 3: top-2 per row (one wave per row) + zero-init outputSPD slots.
// Tie-break: smaller index wins on equal value (matches stable top_k).
// ---------------------------------------------------------------------------
__global__ __launch_bounds__(64) void top2_k(
    const float* __restrict__ outR, int* __restrict__ top2,
    float* __restrict__ outSPD) {
  const int n = blockIdx.x;
  const int lane = threadIdx.x;
  float v1 = -3.0e38f, v2 = -3.0e38f;
  int i1 = 0x7fffffff, i2 = 0x7fffffff;
  for (int o = lane; o < N_DIM; o += 64) {
    float v = outR[n * N_DIM + o];
    if (v > v1 || (v == v1 && o < i1)) {
      v2 = v1; i2 = i1; v1 = v; i1 = o;
    } else if (v > v2 || (v == v2 && o < i2)) {
      v2 = v; i2 = o;
    }
  }
#pragma unroll
  for (int off = 32; off >= 1; off >>= 1) {
    float b1 = __shfl_xor(v1, off, 64);
    int  bi1 = __shfl_xor(i1, off, 64);
    float b2 = __shfl_xor(v2, off, 64);
    int  bi2 = __shfl_xor(i2, off, 64);
    if (b1 > v1 || (b1 == v1 && bi1 < i1)) {
      if (v1 > b2 || (v1 == b2 && i1 < bi2)) { v2 = v1; i2 = i1; }
      else                                   { v2 = b2; i2 = bi2; }
      v1 = b1; i1 = bi1;
    } else if (b1 > v2 || (b1 == v2 && bi1 < i2)) {
      v2 = b1; i2 = bi1;
    }
  }
  if (lane == 0) {
    top2[2 * n]     = i1;
    top2[2 * n + 1] = i2;
    outSPD[4 * n + 0] = 0.f;
    outSPD[4 * n + 1] = 0.f;
    outSPD[4 * n + 2] = 0.f;
    outSPD[4 * n + 3] = 0.f;
  }
}

// ---------------------------------------------------------------------------
// Kernel 4: outputSPD[n,k,m] = sum_{c,d,hw} SPD[n,c,d] * W[ik][d*49+hw] * W[im][c*49+hw]
// 2 blocks per n (c-halves). Per c-tile of 64: U[c, j] = sum_d S[c,d]*B[d,j]
// with B[d, k*49+hw] = W[i_k][d*49+hw] (j padded 98->128 with zeros), then fold
// U against W[i_m][c*49+hw] into 4 per-thread partials; LDS + global atomic reduce.
// ---------------------------------------------------------------------------
__global__ __launch_bounds__(256) void spd_k(
    const float* __restrict__ S, const float* __restrict__ W,
    const int* __restrict__ top2, float* __restrict__ outSPD) {
  __shared__ float St[32][68];    // [dd][c_local], +4 pad, rows 16B-aligned
  __shared__ float Bt[32][128];   // [dd][j]
  __shared__ float red[4];
  const int t    = threadIdx.x;
  const int n    = blockIdx.x >> 1;
  const int half = blockIdx.x & 1;
  const int ia = top2[2 * n];
  const int ib = top2[2 * n + 1];
  const float* Sn = S + (size_t)n * 512 * 512;
  const int tx  = t & 31;       // j-group: j = tx*4 + q
  const int t_y = t >> 5;       // 0..7: c_local = t_y*8 + i
  const int lrow = t >> 3;      // 0..31 (staging)
  const int lcol = (t & 7) << 2;

  if (t < 4) red[t] = 0.f;
  float p00 = 0.f, p01 = 0.f, p10 = 0.f, p11 = 0.f;

  for (int ct = 0; ct < 4; ++ct) {
    const int c0 = half * 256 + ct * 64;
    float u[8][4];
#pragma unroll
    for (int i = 0; i < 8; ++i)
#pragma unroll
      for (int q = 0; q < 4; ++q) u[i][q] = 0.f;

    for (int d0 = 0; d0 < 512; d0 += 32) {
      // stage S^T tile: rows c0..c0+63, cols d0..d0+31
#pragma unroll
      for (int h = 0; h < 2; ++h) {
        const int cl = lrow + 32 * h;
        float4 sv = *(const float4*)(Sn + (size_t)(c0 + cl) * 512 + d0 + lcol);
        St[lcol + 0][cl] = sv.x;
        St[lcol + 1][cl] = sv.y;
        St[lcol + 2][cl] = sv.z;
        St[lcol + 3][cl] = sv.w;
      }
      // stage B tile (zero-padded cols 98..127)
      for (int idx = t; idx < 32 * 128; idx += 256) {
        const int dd = idx >> 7;
        const int j  = idx & 127;
        float val = 0.f;
        if (j < 98) {
          const int kk = (j >= 49);
          const int hw = j - 49 * kk;
          const int wr = kk ? ib : ia;
          val = W[(size_t)wr * K_DIM + (d0 + dd) * 49 + hw];
        }
        Bt[dd][j] = val;
      }
      __syncthreads();
#pragma unroll 8
      for (int dd = 0; dd < 32; ++dd) {
        float s8[8], b4[4];
        *(float4*)&s8[0] = *(const float4*)&St[dd][t_y * 8];
        *(float4*)&s8[4] = *(const float4*)&St[dd][t_y * 8 + 4];
        *(float4*)&b4[0] = *(const float4*)&Bt[dd][tx * 4];
#pragma unroll
        for (int i = 0; i < 8; ++i)
#pragma unroll
          for (int q = 0; q < 4; ++q)
            u[i][q] = fmaf(s8[i], b4[q], u[i][q]);
      }
      __syncthreads();
    }

    // fold: p[k][m] += U_k[c,hw] * W[i_m][c*49+hw]
#pragma unroll
    for (int q = 0; q < 4; ++q) {
      const int j = tx * 4 + q;
      if (j < 98) {
        const int kk = (j >= 49);
        const int hw = j - 49 * kk;
#pragma unroll
        for (int i = 0; i < 8; ++i) {
          const int c = c0 + t_y * 8 + i;
          const float uv = u[i][q];
          const float w0 = W[(size_t)ia * K_DIM + c * 49 + hw];
          const float w1 = W[(size_t)ib * K_DIM + c * 49 + hw];
          if (kk == 0) { p00 = fmaf(uv, w0, p00); p01 = fmaf(uv, w1, p01); }
          else         { p10 = fmaf(uv, w0, p10); p11 = fmaf(uv, w1, p11); }
        }
      }
    }
  }

  atomicAdd(&red[0], p00);
  atomicAdd(&red[1], p01);
  atomicAdd(&red[2], p10);
  atomicAdd(&red[3], p11);
  __syncthreads();
  if (t < 4) atomicAdd(&outSPD[n * 4 + t], red[t]);
}

// ---------------------------------------------------------------------------
extern "C" void kernel_launch(void* const* d_in, const int* in_sizes, int n_in,
                              void* d_out, int out_size, void* d_ws, size_t ws_size,
                              hipStream_t stream) {
  const float* inputR   = (const float*)d_in[0];
  const float* inputSPD = (const float*)d_in[1];
  const float* weight   = (const float*)d_in[2];
  const float* bias     = (const float*)d_in[3];
  float* out = (float*)d_out;

  // workspace layout: [top2 indices: 1024 B][split-K partials: splitk * 1 MB]
  int*   top2 = (int*)d_ws;
  float* part = (float*)((char*)d_ws + 1024);
  const size_t budget = (ws_size > 1024) ? ws_size - 1024 : 0;
  const size_t per_split = (size_t)256 * 1024 * sizeof(float);  // 1 MB
  int splitk = 1;
  {
    const int cands[5] = {32, 16, 8, 4, 2};
    for (int c = 0; c < 5; ++c) {
      if ((size_t)cands[c] * per_split <= budget) { splitk = cands[c]; break; }
    }
  }
  const int kchunk = K_DIM / splitk;  // 25088 divisible by 1..32 pow2

  gemm_partial_k<<<dim3(2, 8, splitk), 256, 0, stream>>>(inputR, weight, part, kchunk);
  reduce_bias_k<<<dim3(1000), 256, 0, stream>>>(part, bias, out, splitk);
  top2_k<<<dim3(256), 64, 0, stream>>>(out, top2, out + 256000);
  spd_k<<<dim3(512), 256, 0, stream>>>(inputSPD, weight, top2, out + 256000);
}

// Round 2
// 862.814 us; speedup vs baseline: 1.2184x; 1.2184x over previous
//
#include <hip/hip_runtime.h>

#define KD 25088   // 512*49
#define N_DIM 1000
#define M_DIM 256

typedef __attribute__((ext_vector_type(8))) short bf16x8;
typedef __attribute__((ext_vector_type(4))) float f32x4;

__device__ inline unsigned short f2bf(float x) {
  union { float f; unsigned u; } v; v.f = x;
  unsigned r = v.u + 0x7FFFu + ((v.u >> 16) & 1);  // RNE
  return (unsigned short)(r >> 16);
}

// ---------------------------------------------------------------------------
// R-path GEMM: C[m,n] partial = sum_k A[m,k]*W[n,k], bf16 MFMA, split-K.
// 128x128 tile, BK=32, 4 waves (2x2), each wave 64x64 via 4x4 of 16x16x32.
// LDS stride 40 ushorts (80 B): 16B-aligned b128 reads, 2-way bank alias (free).
// ---------------------------------------------------------------------------
__global__ __launch_bounds__(256) void rgemm_k(
    const float* __restrict__ A, const float* __restrict__ W,
    float* __restrict__ part, int chunk_steps) {
  __shared__ unsigned short As[128 * 40];
  __shared__ unsigned short Bs[128 * 40];
  const int t = threadIdx.x;
  const int m0 = blockIdx.x * 128;   // 2 tiles
  const int n0 = blockIdx.y * 128;   // 8 tiles (N padded to 1024)
  const int z  = blockIdx.z;
  const int step0 = z * chunk_steps;
  const int lane = t & 63, w = t >> 6;
  const int cw = (w >> 1) * 64, jw = (w & 1) * 64;
  const int r16 = lane & 15, quad = lane >> 4;

  f32x4 acc[4][4];
#pragma unroll
  for (int i = 0; i < 4; ++i)
#pragma unroll
    for (int j = 0; j < 4; ++j) {
      acc[i][j][0] = 0.f; acc[i][j][1] = 0.f;
      acc[i][j][2] = 0.f; acc[i][j][3] = 0.f;
    }

  for (int s = 0; s < chunk_steps; ++s) {
    const int kbase = (step0 + s) * 32;
    // stage A (128x32) and B (128x32) as bf16, float4 global loads
#pragma unroll
    for (int h = 0; h < 4; ++h) {
      const int idx = h * 256 + t;       // 0..1023 float4 slots
      const int row = idx >> 3;
      const int c4  = (idx & 7) << 2;
      float4 av = *(const float4*)(A + (size_t)(m0 + row) * KD + kbase + c4);
      uint2 pa;
      pa.x = f2bf(av.x) | ((unsigned)f2bf(av.y) << 16);
      pa.y = f2bf(av.z) | ((unsigned)f2bf(av.w) << 16);
      *(uint2*)&As[row * 40 + c4] = pa;
      const int wr = n0 + row;
      float4 wv = make_float4(0.f, 0.f, 0.f, 0.f);
      if (wr < N_DIM) wv = *(const float4*)(W + (size_t)wr * KD + kbase + c4);
      uint2 pb;
      pb.x = f2bf(wv.x) | ((unsigned)f2bf(wv.y) << 16);
      pb.y = f2bf(wv.z) | ((unsigned)f2bf(wv.w) << 16);
      *(uint2*)&Bs[row * 40 + c4] = pb;
    }
    __syncthreads();
    bf16x8 af[4], bq[4];
#pragma unroll
    for (int i = 0; i < 4; ++i) {
      af[i] = *(const bf16x8*)&As[(cw + i * 16 + r16) * 40 + quad * 8];
      bq[i] = *(const bf16x8*)&Bs[(jw + i * 16 + r16) * 40 + quad * 8];
    }
#pragma unroll
    for (int i = 0; i < 4; ++i)
#pragma unroll
      for (int j = 0; j < 4; ++j)
        acc[i][j] = __builtin_amdgcn_mfma_f32_16x16x32_bf16(af[i], bq[j], acc[i][j], 0, 0, 0);
    __syncthreads();
  }

  // epilogue: C layout col=lane&15 (n), row=quad*4+r (m)   [m89-verified]
  float* pb = part + (size_t)z * 256 * 1024;
#pragma unroll
  for (int i = 0; i < 4; ++i)
#pragma unroll
    for (int j = 0; j < 4; ++j) {
      const int n = n0 + jw + j * 16 + r16;
#pragma unroll
      for (int r = 0; r < 4; ++r) {
        const int m = m0 + cw + i * 16 + quad * 4 + r;
        pb[(size_t)m * 1024 + n] = acc[i][j][r];
      }
    }
}

// ---------------------------------------------------------------------------
// reduce split-K partials + bias -> outputR
// ---------------------------------------------------------------------------
__global__ __launch_bounds__(256) void reduce_bias_k(
    const float* __restrict__ part, const float* __restrict__ bias,
    float* __restrict__ outR, int splitk) {
  const int id = blockIdx.x * 256 + threadIdx.x;
  if (id >= M_DIM * N_DIM) return;
  const int n = id / N_DIM;
  const int o = id - n * N_DIM;
  float s = 0.f;
  for (int z = 0; z < splitk; ++z)
    s += part[((size_t)z * 256 + n) * 1024 + o];
  outR[id] = s + bias[o];
}

// ---------------------------------------------------------------------------
// top-8 per row (one wave per row); writes provisional top2, candidate list,
// and a recheck flag when bf16 noise could flip the selection/order.
// Also zero-inits the outputSPD slots.
// ---------------------------------------------------------------------------
__global__ __launch_bounds__(64) void top8_k(
    const float* __restrict__ outR, int* __restrict__ top2,
    int* __restrict__ candIdx, int* __restrict__ flags,
    float* __restrict__ outSPD) {
  const int n = blockIdx.x;
  const int lane = threadIdx.x;
  float v[16];
#pragma unroll
  for (int r = 0; r < 16; ++r) {
    const int o = lane + r * 64;
    v[r] = (o < N_DIM) ? outR[n * N_DIM + o] : -3.0e38f;
  }
  float cv[8]; int ci[8];
#pragma unroll
  for (int rr = 0; rr < 8; ++rr) {
    float bv = -3.0e38f; int bi = 0x3fffffff;
#pragma unroll
    for (int r = 0; r < 16; ++r) {
      const int o = lane + r * 64;
      if (v[r] > bv || (v[r] == bv && o < bi)) { bv = v[r]; bi = o; }
    }
#pragma unroll
    for (int off = 32; off >= 1; off >>= 1) {
      const float ov = __shfl_xor(bv, off, 64);
      const int   oi = __shfl_xor(bi, off, 64);
      if (ov > bv || (ov == bv && oi < bi)) { bv = ov; bi = oi; }
    }
    cv[rr] = bv; ci[rr] = bi;
#pragma unroll
    for (int r = 0; r < 16; ++r)
      if (lane + r * 64 == bi) v[r] = -3.0e38f;
  }
  if (lane == 0) {
    const bool safe = (cv[0] - cv[1] >= 0.025f) &&
                      (cv[1] - cv[2] >= 0.025f) &&
                      (cv[1] - cv[7] >= 0.06f);
    flags[n] = safe ? 0 : 1;
    top2[2 * n]     = ci[0];
    top2[2 * n + 1] = ci[1];
#pragma unroll
    for (int r = 0; r < 8; ++r) candIdx[n * 8 + r] = ci[r];
    outSPD[4 * n + 0] = 0.f; outSPD[4 * n + 1] = 0.f;
    outSPD[4 * n + 2] = 0.f; outSPD[4 * n + 3] = 0.f;
  }
}

// ---------------------------------------------------------------------------
// exact fp32 recheck of the 8 candidates for flagged rows; rewrites top2.
// ---------------------------------------------------------------------------
__global__ __launch_bounds__(256) void recheck_k(
    const float* __restrict__ A, const float* __restrict__ W,
    const float* __restrict__ bias, const int* __restrict__ candIdx,
    const int* __restrict__ flags, int* __restrict__ top2) {
  const int n = blockIdx.x;
  if (!flags[n]) return;
  __shared__ float red[4];
  __shared__ float vals[8];
  const int t = threadIdx.x;
  const int lane = t & 63, w = t >> 6;
  for (int c = 0; c < 8; ++c) {
    const int idx = candIdx[n * 8 + c];
    float s = 0.f;
    for (int i = t; i < KD; i += 256)
      s += A[(size_t)n * KD + i] * W[(size_t)idx * KD + i];
#pragma unroll
    for (int off = 32; off >= 1; off >>= 1) s += __shfl_xor(s, off, 64);
    if (lane == 0) red[w] = s;
    __syncthreads();
    if (t == 0) vals[c] = red[0] + red[1] + red[2] + red[3] + bias[idx];
    __syncthreads();
  }
  if (t == 0) {
    int b0 = -1; float v0 = -3.0e38f; int i0 = 0x3fffffff;
    for (int c = 0; c < 8; ++c) {
      const int idx = candIdx[n * 8 + c];
      if (vals[c] > v0 || (vals[c] == v0 && idx < i0)) { v0 = vals[c]; i0 = idx; b0 = c; }
    }
    float v1 = -3.0e38f; int i1 = 0x3fffffff;
    for (int c = 0; c < 8; ++c) {
      if (c == b0) continue;
      const int idx = candIdx[n * 8 + c];
      if (vals[c] > v1 || (vals[c] == v1 && idx < i1)) { v1 = vals[c]; i1 = idx; }
    }
    top2[2 * n]     = i0;
    top2[2 * n + 1] = i1;
  }
}

// ---------------------------------------------------------------------------
// SPD path: per (n, c-tile of 128): U[c,j] = sum_d S[n,c,d]*Wsel(j)[d,hw(j)]
// via bf16 MFMA (M=c 128, N=j 98->128, K=d 512), then fold
// p[k][m] += U[c, k*49+hw] * W[i_m][c*49+hw] from C fragments, atomic reduce.
// ---------------------------------------------------------------------------
__global__ __launch_bounds__(256) void spd_k(
    const float* __restrict__ S, const float* __restrict__ W,
    const int* __restrict__ top2, float* __restrict__ outSPD) {
  __shared__ unsigned short As[128 * 40];
  __shared__ unsigned short Bs[128 * 40];
  __shared__ float red[4];
  const int t = threadIdx.x;
  const int n  = blockIdx.x >> 2;
  const int c0 = (blockIdx.x & 3) * 128;
  const int ia = top2[2 * n];
  const int ib = top2[2 * n + 1];
  const float* Sn = S + (size_t)n * 512 * 512;
  const int lane = t & 63, w = t >> 6;
  const int cw = (w >> 1) * 64, jw = (w & 1) * 64;
  const int r16 = lane & 15, quad = lane >> 4;

  if (t < 4) red[t] = 0.f;

  f32x4 acc[4][4];
#pragma unroll
  for (int i = 0; i < 4; ++i)
#pragma unroll
    for (int j = 0; j < 4; ++j) {
      acc[i][j][0] = 0.f; acc[i][j][1] = 0.f;
      acc[i][j][2] = 0.f; acc[i][j][3] = 0.f;
    }

  // B-stage thread mapping (constant across K loop)
  const int bj   = t & 127;           // j row
  const int bh   = t >> 7;            // 0/1 -> dd half
  const int bkk  = (bj >= 49);
  const int bhw  = bj - 49 * bkk;
  const bool bvalid = (bj < 98);
  const float* brow = W + (size_t)(bkk ? ib : ia) * KD + bhw;

  for (int d0 = 0; d0 < 512; d0 += 32) {
    // stage A: S[c0..c0+127][d0..d0+31] -> bf16
#pragma unroll
    for (int h = 0; h < 4; ++h) {
      const int idx = h * 256 + t;
      const int row = idx >> 3;
      const int c4  = (idx & 7) << 2;
      float4 av = *(const float4*)(Sn + (size_t)(c0 + row) * 512 + d0 + c4);
      uint2 pa;
      pa.x = f2bf(av.x) | ((unsigned)f2bf(av.y) << 16);
      pa.y = f2bf(av.z) | ((unsigned)f2bf(av.w) << 16);
      *(uint2*)&As[row * 40 + c4] = pa;
    }
    // stage B: Bs[j][dd] = W[sel(j)][(d0+dd)*49 + hw(j)], zero-pad j>=98
#pragma unroll
    for (int dd2 = 0; dd2 < 16; dd2 += 2) {
      const int dd = bh * 16 + dd2;
      const float x0 = bvalid ? brow[(size_t)(d0 + dd) * 49] : 0.f;
      const float x1 = bvalid ? brow[(size_t)(d0 + dd + 1) * 49] : 0.f;
      const unsigned pk = f2bf(x0) | ((unsigned)f2bf(x1) << 16);
      *(unsigned*)&Bs[bj * 40 + dd] = pk;
    }
    __syncthreads();
    bf16x8 af[4], bq[4];
#pragma unroll
    for (int i = 0; i < 4; ++i) {
      af[i] = *(const bf16x8*)&As[(cw + i * 16 + r16) * 40 + quad * 8];
      bq[i] = *(const bf16x8*)&Bs[(jw + i * 16 + r16) * 40 + quad * 8];
    }
#pragma unroll
    for (int i = 0; i < 4; ++i)
#pragma unroll
      for (int j = 0; j < 4; ++j)
        acc[i][j] = __builtin_amdgcn_mfma_f32_16x16x32_bf16(af[i], bq[j], acc[i][j], 0, 0, 0);
    __syncthreads();
  }

  // fold: C layout col=lane&15 (j), row=quad*4+r (c)   [m89-verified]
  float p00 = 0.f, p01 = 0.f, p10 = 0.f, p11 = 0.f;
  const float* Wa = W + (size_t)ia * KD;
  const float* Wb = W + (size_t)ib * KD;
#pragma unroll
  for (int j = 0; j < 4; ++j) {
    const int jj = jw + j * 16 + r16;
    if (jj < 98) {
      const int kk = (jj >= 49);
      const int hw = jj - 49 * kk;
#pragma unroll
      for (int i = 0; i < 4; ++i) {
#pragma unroll
        for (int r = 0; r < 4; ++r) {
          const int c = c0 + cw + i * 16 + quad * 4 + r;
          const float u  = acc[i][j][r];
          const float wa = Wa[(size_t)c * 49 + hw];
          const float wb = Wb[(size_t)c * 49 + hw];
          if (kk == 0) { p00 = fmaf(u, wa, p00); p01 = fmaf(u, wb, p01); }
          else         { p10 = fmaf(u, wa, p10); p11 = fmaf(u, wb, p11); }
        }
      }
    }
  }

  atomicAdd(&red[0], p00);
  atomicAdd(&red[1], p01);
  atomicAdd(&red[2], p10);
  atomicAdd(&red[3], p11);
  __syncthreads();
  if (t < 4) atomicAdd(&outSPD[n * 4 + t], red[t]);
}

// ---------------------------------------------------------------------------
extern "C" void kernel_launch(void* const* d_in, const int* in_sizes, int n_in,
                              void* d_out, int out_size, void* d_ws, size_t ws_size,
                              hipStream_t stream) {
  const float* inputR   = (const float*)d_in[0];
  const float* inputSPD = (const float*)d_in[1];
  const float* weight   = (const float*)d_in[2];
  const float* bias     = (const float*)d_in[3];
  float* out = (float*)d_out;

  // ws layout: [top2 2 KB][candIdx 8 KB][flags 1 KB][pad to 64 KB][partials]
  int*   top2    = (int*)d_ws;
  int*   candIdx = (int*)((char*)d_ws + 2048);
  int*   flags   = (int*)((char*)d_ws + 2048 + 8192);
  float* part    = (float*)((char*)d_ws + 65536);
  const size_t budget = (ws_size > 65536) ? ws_size - 65536 : 0;
  const size_t per_split = (size_t)256 * 1024 * sizeof(float);  // 1 MB
  int splitk = 1;
  {
    const int cands[7] = {28, 14, 8, 7, 4, 2, 1};  // divisors of 784 K-steps
    for (int c = 0; c < 7; ++c)
      if ((size_t)cands[c] * per_split <= budget) { splitk = cands[c]; break; }
  }
  const int chunk_steps = 784 / splitk;

  rgemm_k<<<dim3(2, 8, splitk), 256, 0, stream>>>(inputR, weight, part, chunk_steps);
  reduce_bias_k<<<dim3(1001), 256, 0, stream>>>(part, bias, out, splitk);
  top8_k<<<dim3(256), 64, 0, stream>>>(out, top2, candIdx, flags, out + 256000);
  recheck_k<<<dim3(256), 256, 0, stream>>>(inputR, weight, bias, candIdx, flags, top2);
  spd_k<<<dim3(1024), 256, 0, stream>>>(inputSPD, weight, top2, out + 256000);
}

// Round 3
// 655.538 us; speedup vs baseline: 1.6036x; 1.3162x over previous
//
#include <hip/hip_runtime.h>

#define KD 25088   // 512*49
#define N_DIM 1000

typedef __attribute__((ext_vector_type(8))) short bf16x8;
typedef __attribute__((ext_vector_type(4))) float f32x4;

__device__ inline unsigned short f2bf(float x) {
  union { float f; unsigned u; } v; v.f = x;
  unsigned r = v.u + 0x7FFFu + ((v.u >> 16) & 1);  // RNE
  return (unsigned short)(r >> 16);
}
__device__ inline unsigned pack2(float a, float b) {
  return (unsigned)f2bf(a) | ((unsigned)f2bf(b) << 16);
}
__device__ inline float bf2f(unsigned short u) {
  union { unsigned u; float f; } v; v.u = ((unsigned)u) << 16; return v.f;
}

// ---------------------------------------------------------------------------
// outR[m,n] = bias[n]  (rgemm then atomically accumulates partial dots)
// ---------------------------------------------------------------------------
__global__ __launch_bounds__(256) void init_bias_k(
    const float* __restrict__ bias, float* __restrict__ outR) {
  const int id = blockIdx.x * 256 + threadIdx.x;
  if (id < 256 * N_DIM) outR[id] = bias[id % N_DIM];
}

// ---------------------------------------------------------------------------
// R-GEMM: fixed 28-way split-K, fp32 atomics into outR. Double-buffered LDS,
// inline fp32->bf16 conversion during staging. 128x128 tile, BK=32, 4 waves,
// LDS row stride 32 shorts (64 B, no pad: 2-way bank alias is free).
// ---------------------------------------------------------------------------
__global__ __launch_bounds__(256) void rgemm_k(
    const float* __restrict__ A, const float* __restrict__ W,
    float* __restrict__ outR) {
  __shared__ unsigned short As[2][128 * 32];
  __shared__ unsigned short Bs[2][128 * 32];
  const int t = threadIdx.x;
  const int m0 = blockIdx.x * 128;   // 2 m-tiles
  const int n0 = blockIdx.y * 128;   // 8 n-tiles (N padded)
  const int z  = blockIdx.z;         // 0..27
  const int lane = t & 63, w = t >> 6;
  const int cw = (w >> 1) * 64, jw = (w & 1) * 64;
  const int r16 = lane & 15, quad = lane >> 4;
  const int srow = t >> 2;           // 0..63
  const int sc8  = (t & 3) << 3;     // 0,8,16,24

  float a_pre[16], b_pre[16];

  f32x4 acc[4][4];
#pragma unroll
  for (int i = 0; i < 4; ++i)
#pragma unroll
    for (int j = 0; j < 4; ++j) {
      acc[i][j][0] = 0.f; acc[i][j][1] = 0.f;
      acc[i][j][2] = 0.f; acc[i][j][3] = 0.f;
    }

#define RG_LOAD(s_)                                                         \
  {                                                                         \
    const int kbase = ((z) * 28 + (s_)) * 32;                               \
    _Pragma("unroll")                                                       \
    for (int h = 0; h < 2; ++h) {                                           \
      const int row = h * 64 + srow;                                        \
      const float* pa = A + (size_t)(m0 + row) * KD + kbase + sc8;          \
      *(float4*)&a_pre[h * 8 + 0] = *(const float4*)pa;                     \
      *(float4*)&a_pre[h * 8 + 4] = *(const float4*)(pa + 4);               \
      const int wr = n0 + row;                                              \
      if (wr < N_DIM) {                                                     \
        const float* pw = W + (size_t)wr * KD + kbase + sc8;                \
        *(float4*)&b_pre[h * 8 + 0] = *(const float4*)pw;                   \
        *(float4*)&b_pre[h * 8 + 4] = *(const float4*)(pw + 4);             \
      } else {                                                              \
        _Pragma("unroll")                                                   \
        for (int q = 0; q < 8; ++q) b_pre[h * 8 + q] = 0.f;                 \
      }                                                                     \
    }                                                                       \
  }

#define RG_WRITE(p_)                                                        \
  {                                                                         \
    _Pragma("unroll")                                                       \
    for (int h = 0; h < 2; ++h) {                                           \
      const int row = h * 64 + srow;                                        \
      uint4 ua, ub;                                                         \
      ua.x = pack2(a_pre[h*8+0], a_pre[h*8+1]);                             \
      ua.y = pack2(a_pre[h*8+2], a_pre[h*8+3]);                             \
      ua.z = pack2(a_pre[h*8+4], a_pre[h*8+5]);                             \
      ua.w = pack2(a_pre[h*8+6], a_pre[h*8+7]);                             \
      ub.x = pack2(b_pre[h*8+0], b_pre[h*8+1]);                             \
      ub.y = pack2(b_pre[h*8+2], b_pre[h*8+3]);                             \
      ub.z = pack2(b_pre[h*8+4], b_pre[h*8+5]);                             \
      ub.w = pack2(b_pre[h*8+6], b_pre[h*8+7]);                             \
      *(uint4*)&As[p_][row * 32 + sc8] = ua;                                \
      *(uint4*)&Bs[p_][row * 32 + sc8] = ub;                                \
    }                                                                       \
  }

  RG_LOAD(0); RG_WRITE(0); __syncthreads();
  int p = 0;
  for (int s = 0; s < 28; ++s) {
    if (s + 1 < 28) RG_LOAD(s + 1);
    bf16x8 af[4], bq[4];
#pragma unroll
    for (int i = 0; i < 4; ++i) {
      af[i] = *(const bf16x8*)&As[p][(cw + i * 16 + r16) * 32 + quad * 8];
      bq[i] = *(const bf16x8*)&Bs[p][(jw + i * 16 + r16) * 32 + quad * 8];
    }
#pragma unroll
    for (int i = 0; i < 4; ++i)
#pragma unroll
      for (int j = 0; j < 4; ++j)
        acc[i][j] = __builtin_amdgcn_mfma_f32_16x16x32_bf16(af[i], bq[j], acc[i][j], 0, 0, 0);
    if (s + 1 < 28) RG_WRITE(p ^ 1);
    __syncthreads();
    p ^= 1;
  }

  // epilogue: C layout col=lane&15 (n), row=quad*4+r (m)   [m89-verified]
#pragma unroll
  for (int j = 0; j < 4; ++j) {
    const int n = n0 + jw + j * 16 + r16;
    if (n < N_DIM) {
#pragma unroll
      for (int i = 0; i < 4; ++i)
#pragma unroll
        for (int r = 0; r < 4; ++r) {
          const int m = m0 + cw + i * 16 + quad * 4 + r;
          atomicAdd(&outR[(size_t)m * N_DIM + n], acc[i][j][r]);
        }
    }
  }
#undef RG_LOAD
#undef RG_WRITE
}

// ---------------------------------------------------------------------------
// top-8 per row; provisional top2 + candidates + recheck flag; zero outSPD.
// ---------------------------------------------------------------------------
__global__ __launch_bounds__(64) void top8_k(
    const float* __restrict__ outR, int* __restrict__ top2,
    int* __restrict__ candIdx, int* __restrict__ flags,
    float* __restrict__ outSPD) {
  const int n = blockIdx.x;
  const int lane = threadIdx.x;
  float v[16];
#pragma unroll
  for (int r = 0; r < 16; ++r) {
    const int o = lane + r * 64;
    v[r] = (o < N_DIM) ? outR[n * N_DIM + o] : -3.0e38f;
  }
  float cv[8]; int ci[8];
#pragma unroll
  for (int rr = 0; rr < 8; ++rr) {
    float bv = -3.0e38f; int bi = 0x3fffffff;
#pragma unroll
    for (int r = 0; r < 16; ++r) {
      const int o = lane + r * 64;
      if (v[r] > bv || (v[r] == bv && o < bi)) { bv = v[r]; bi = o; }
    }
#pragma unroll
    for (int off = 32; off >= 1; off >>= 1) {
      const float ov = __shfl_xor(bv, off, 64);
      const int   oi = __shfl_xor(bi, off, 64);
      if (ov > bv || (ov == bv && oi < bi)) { bv = ov; bi = oi; }
    }
    cv[rr] = bv; ci[rr] = bi;
#pragma unroll
    for (int r = 0; r < 16; ++r)
      if (lane + r * 64 == bi) v[r] = -3.0e38f;
  }
  if (lane == 0) {
    const bool safe = (cv[0] - cv[1] >= 0.025f) &&
                      (cv[1] - cv[2] >= 0.025f) &&
                      (cv[1] - cv[7] >= 0.05f);
    flags[n] = safe ? 0 : 1;
    top2[2 * n]     = ci[0];
    top2[2 * n + 1] = ci[1];
#pragma unroll
    for (int r = 0; r < 8; ++r) candIdx[n * 8 + r] = ci[r];
    outSPD[4 * n + 0] = 0.f; outSPD[4 * n + 1] = 0.f;
    outSPD[4 * n + 2] = 0.f; outSPD[4 * n + 3] = 0.f;
  }
}

// ---------------------------------------------------------------------------
// exact fp32 dot for flagged (n, candidate) pairs -> vals[n*8+c]
// ---------------------------------------------------------------------------
__global__ __launch_bounds__(256) void rdot_k(
    const float* __restrict__ A, const float* __restrict__ W,
    const float* __restrict__ bias, const int* __restrict__ candIdx,
    const int* __restrict__ flags, float* __restrict__ vals) {
  const int n = blockIdx.x;
  if (!flags[n]) return;
  const int c = blockIdx.y;
  const int idx = candIdx[n * 8 + c];
  const float4* a4 = (const float4*)(A + (size_t)n * KD);
  const float4* w4 = (const float4*)(W + (size_t)idx * KD);
  float s = 0.f;
  for (int i = threadIdx.x; i < KD / 4; i += 256) {
    const float4 av = a4[i];
    const float4 wv = w4[i];
    s += av.x * wv.x + av.y * wv.y + av.z * wv.z + av.w * wv.w;
  }
#pragma unroll
  for (int off = 32; off >= 1; off >>= 1) s += __shfl_xor(s, off, 64);
  __shared__ float red[4];
  const int lane = threadIdx.x & 63, w = threadIdx.x >> 6;
  if (lane == 0) red[w] = s;
  __syncthreads();
  if (threadIdx.x == 0)
    vals[n * 8 + c] = red[0] + red[1] + red[2] + red[3] + bias[idx];
}

// ---------------------------------------------------------------------------
// final top-2 from exact vals for flagged rows
// ---------------------------------------------------------------------------
__global__ __launch_bounds__(64) void select_k(
    const float* __restrict__ vals, const int* __restrict__ candIdx,
    const int* __restrict__ flags, int* __restrict__ top2) {
  const int n = blockIdx.x;
  if (threadIdx.x != 0 || !flags[n]) return;
  int b0 = -1; float v0 = -3.0e38f; int i0 = 0x3fffffff;
  for (int c = 0; c < 8; ++c) {
    const int idx = candIdx[n * 8 + c];
    const float vv = vals[n * 8 + c];
    if (vv > v0 || (vv == v0 && idx < i0)) { v0 = vv; i0 = idx; b0 = c; }
  }
  float v1 = -3.0e38f; int i1 = 0x3fffffff;
  for (int c = 0; c < 8; ++c) {
    if (c == b0) continue;
    const int idx = candIdx[n * 8 + c];
    const float vv = vals[n * 8 + c];
    if (vv > v1 || (vv == v1 && idx < i1)) { v1 = vv; i1 = idx; }
  }
  top2[2 * n]     = i0;
  top2[2 * n + 1] = i1;
}

// ---------------------------------------------------------------------------
// pack selected weight rows: Wp[n][j][d] (bf16, j<128 pad, d<512)
//   j = k*49+hw  ->  W[sel_k][d*49+hw];  rows j>=98 zeroed.
// ---------------------------------------------------------------------------
__global__ __launch_bounds__(256) void pack_k(
    const float* __restrict__ W, const int* __restrict__ top2,
    unsigned short* __restrict__ Wp) {
  const int n  = blockIdx.x;
  const int jq = blockIdx.y;           // 0..3 -> 32 j-rows each
  const int ia = top2[2 * n];
  const int ib = top2[2 * n + 1];
  unsigned short* dst = Wp + (size_t)n * 65536;
  for (int u = threadIdx.x; u < 32 * 256; u += 256) {
    const int j  = jq * 32 + (u >> 8);
    const int d2 = (u & 255) * 2;
    unsigned val = 0u;
    if (j < 98) {
      const int kk = (j >= 49);
      const int hw = j - 49 * kk;
      const float* wr = W + (size_t)(kk ? ib : ia) * KD + hw;
      val = pack2(wr[(size_t)d2 * 49], wr[(size_t)(d2 + 1) * 49]);
    }
    *(unsigned*)(dst + j * 512 + d2) = val;
  }
}

// ---------------------------------------------------------------------------
// SPD fast path: per (n, c-tile 128): U = S_tile x Wp^T via bf16 MFMA,
// double-buffered LDS, then fold into 2x2 with bf16 Wp reads, atomic reduce.
// ---------------------------------------------------------------------------
__global__ __launch_bounds__(256) void spd_k(
    const float* __restrict__ S, const unsigned short* __restrict__ Wp,
    float* __restrict__ outSPD) {
  __shared__ unsigned short As[2][128 * 32];
  __shared__ unsigned short Bs[2][128 * 32];
  __shared__ float red[4];
  const int t = threadIdx.x;
  const int n  = blockIdx.x >> 2;
  const int c0 = (blockIdx.x & 3) * 128;
  const float* Sn = S + (size_t)n * 512 * 512;
  const unsigned short* Wpn = Wp + (size_t)n * 65536;
  const int lane = t & 63, w = t >> 6;
  const int cw = (w >> 1) * 64, jw = (w & 1) * 64;
  const int r16 = lane & 15, quad = lane >> 4;
  const int srow = t >> 2;
  const int sc8  = (t & 3) << 3;

  if (t < 4) red[t] = 0.f;

  float a_pre[16];
  uint4 b_pre[2];

  f32x4 acc[4][4];
#pragma unroll
  for (int i = 0; i < 4; ++i)
#pragma unroll
    for (int j = 0; j < 4; ++j) {
      acc[i][j][0] = 0.f; acc[i][j][1] = 0.f;
      acc[i][j][2] = 0.f; acc[i][j][3] = 0.f;
    }

#define SP_LOAD(s_)                                                         \
  {                                                                         \
    const int d0 = (s_) * 32;                                               \
    _Pragma("unroll")                                                       \
    for (int h = 0; h < 2; ++h) {                                           \
      const int row = h * 64 + srow;                                        \
      const float* pa = Sn + (size_t)(c0 + row) * 512 + d0 + sc8;           \
      *(float4*)&a_pre[h * 8 + 0] = *(const float4*)pa;                     \
      *(float4*)&a_pre[h * 8 + 4] = *(const float4*)(pa + 4);               \
      b_pre[h] = *(const uint4*)(Wpn + (size_t)row * 512 + d0 + sc8);       \
    }                                                                       \
  }

#define SP_WRITE(p_)                                                        \
  {                                                                         \
    _Pragma("unroll")                                                       \
    for (int h = 0; h < 2; ++h) {                                           \
      const int row = h * 64 + srow;                                        \
      uint4 ua;                                                             \
      ua.x = pack2(a_pre[h*8+0], a_pre[h*8+1]);                             \
      ua.y = pack2(a_pre[h*8+2], a_pre[h*8+3]);                             \
      ua.z = pack2(a_pre[h*8+4], a_pre[h*8+5]);                             \
      ua.w = pack2(a_pre[h*8+6], a_pre[h*8+7]);                             \
      *(uint4*)&As[p_][row * 32 + sc8] = ua;                                \
      *(uint4*)&Bs[p_][row * 32 + sc8] = b_pre[h];                          \
    }                                                                       \
  }

  SP_LOAD(0); SP_WRITE(0); __syncthreads();
  int p = 0;
  for (int s = 0; s < 16; ++s) {
    if (s + 1 < 16) SP_LOAD(s + 1);
    bf16x8 af[4], bq[4];
#pragma unroll
    for (int i = 0; i < 4; ++i) {
      af[i] = *(const bf16x8*)&As[p][(cw + i * 16 + r16) * 32 + quad * 8];
      bq[i] = *(const bf16x8*)&Bs[p][(jw + i * 16 + r16) * 32 + quad * 8];
    }
#pragma unroll
    for (int i = 0; i < 4; ++i)
#pragma unroll
      for (int j = 0; j < 4; ++j)
        acc[i][j] = __builtin_amdgcn_mfma_f32_16x16x32_bf16(af[i], bq[j], acc[i][j], 0, 0, 0);
    if (s + 1 < 16) SP_WRITE(p ^ 1);
    __syncthreads();
    p ^= 1;
  }
#undef SP_LOAD
#undef SP_WRITE

  // fold: C layout col=lane&15 (j), row=quad*4+r (c)
  float p00 = 0.f, p01 = 0.f, p10 = 0.f, p11 = 0.f;
#pragma unroll
  for (int j = 0; j < 4; ++j) {
    const int jj = jw + j * 16 + r16;
    if (jj < 98) {
      const int kk = (jj >= 49);
      const int hw = jj - 49 * kk;
      const unsigned short* wa = Wpn + (size_t)hw * 512;         // W[ia][c,hw]
      const unsigned short* wb = Wpn + (size_t)(49 + hw) * 512;  // W[ib][c,hw]
#pragma unroll
      for (int i = 0; i < 4; ++i) {
#pragma unroll
        for (int r = 0; r < 4; ++r) {
          const int c = c0 + cw + i * 16 + quad * 4 + r;
          const float u   = acc[i][j][r];
          const float wav = bf2f(wa[c]);
          const float wbv = bf2f(wb[c]);
          if (kk == 0) { p00 = fmaf(u, wav, p00); p01 = fmaf(u, wbv, p01); }
          else         { p10 = fmaf(u, wav, p10); p11 = fmaf(u, wbv, p11); }
        }
      }
    }
  }

  atomicAdd(&red[0], p00);
  atomicAdd(&red[1], p01);
  atomicAdd(&red[2], p10);
  atomicAdd(&red[3], p11);
  __syncthreads();
  if (t < 4) atomicAdd(&outSPD[n * 4 + t], red[t]);
}

// ---------------------------------------------------------------------------
// SPD fallback (round-2 style, no Wp workspace needed)
// ---------------------------------------------------------------------------
__global__ __launch_bounds__(256) void spd_fb_k(
    const float* __restrict__ S, const float* __restrict__ W,
    const int* __restrict__ top2, float* __restrict__ outSPD) {
  __shared__ unsigned short As[128 * 40];
  __shared__ unsigned short Bs[128 * 40];
  __shared__ float red[4];
  const int t = threadIdx.x;
  const int n  = blockIdx.x >> 2;
  const int c0 = (blockIdx.x & 3) * 128;
  const int ia = top2[2 * n];
  const int ib = top2[2 * n + 1];
  const float* Sn = S + (size_t)n * 512 * 512;
  const int lane = t & 63, w = t >> 6;
  const int cw = (w >> 1) * 64, jw = (w & 1) * 64;
  const int r16 = lane & 15, quad = lane >> 4;
  if (t < 4) red[t] = 0.f;
  f32x4 acc[4][4];
#pragma unroll
  for (int i = 0; i < 4; ++i)
#pragma unroll
    for (int j = 0; j < 4; ++j) {
      acc[i][j][0] = 0.f; acc[i][j][1] = 0.f;
      acc[i][j][2] = 0.f; acc[i][j][3] = 0.f;
    }
  const int bj  = t & 127;
  const int bh  = t >> 7;
  const int bkk = (bj >= 49);
  const int bhw = bj - 49 * bkk;
  const bool bvalid = (bj < 98);
  const float* brow = W + (size_t)(bkk ? ib : ia) * KD + bhw;
  for (int d0 = 0; d0 < 512; d0 += 32) {
#pragma unroll
    for (int h = 0; h < 4; ++h) {
      const int idx = h * 256 + t;
      const int row = idx >> 3;
      const int c4  = (idx & 7) << 2;
      float4 av = *(const float4*)(Sn + (size_t)(c0 + row) * 512 + d0 + c4);
      uint2 pa;
      pa.x = pack2(av.x, av.y);
      pa.y = pack2(av.z, av.w);
      *(uint2*)&As[row * 40 + c4] = pa;
    }
#pragma unroll
    for (int dd2 = 0; dd2 < 16; dd2 += 2) {
      const int dd = bh * 16 + dd2;
      const float x0 = bvalid ? brow[(size_t)(d0 + dd) * 49] : 0.f;
      const float x1 = bvalid ? brow[(size_t)(d0 + dd + 1) * 49] : 0.f;
      *(unsigned*)&Bs[bj * 40 + dd] = pack2(x0, x1);
    }
    __syncthreads();
    bf16x8 af[4], bq[4];
#pragma unroll
    for (int i = 0; i < 4; ++i) {
      af[i] = *(const bf16x8*)&As[(cw + i * 16 + r16) * 40 + quad * 8];
      bq[i] = *(const bf16x8*)&Bs[(jw + i * 16 + r16) * 40 + quad * 8];
    }
#pragma unroll
    for (int i = 0; i < 4; ++i)
#pragma unroll
      for (int j = 0; j < 4; ++j)
        acc[i][j] = __builtin_amdgcn_mfma_f32_16x16x32_bf16(af[i], bq[j], acc[i][j], 0, 0, 0);
    __syncthreads();
  }
  float p00 = 0.f, p01 = 0.f, p10 = 0.f, p11 = 0.f;
  const float* Wa = W + (size_t)ia * KD;
  const float* Wb = W + (size_t)ib * KD;
#pragma unroll
  for (int j = 0; j < 4; ++j) {
    const int jj = jw + j * 16 + r16;
    if (jj < 98) {
      const int kk = (jj >= 49);
      const int hw = jj - 49 * kk;
#pragma unroll
      for (int i = 0; i < 4; ++i)
#pragma unroll
        for (int r = 0; r < 4; ++r) {
          const int c = c0 + cw + i * 16 + quad * 4 + r;
          const float u  = acc[i][j][r];
          const float wa = Wa[(size_t)c * 49 + hw];
          const float wb = Wb[(size_t)c * 49 + hw];
          if (kk == 0) { p00 = fmaf(u, wa, p00); p01 = fmaf(u, wb, p01); }
          else         { p10 = fmaf(u, wa, p10); p11 = fmaf(u, wb, p11); }
        }
    }
  }
  atomicAdd(&red[0], p00);
  atomicAdd(&red[1], p01);
  atomicAdd(&red[2], p10);
  atomicAdd(&red[3], p11);
  __syncthreads();
  if (t < 4) atomicAdd(&outSPD[n * 4 + t], red[t]);
}

// ---------------------------------------------------------------------------
extern "C" void kernel_launch(void* const* d_in, const int* in_sizes, int n_in,
                              void* d_out, int out_size, void* d_ws, size_t ws_size,
                              hipStream_t stream) {
  const float* inputR   = (const float*)d_in[0];
  const float* inputSPD = (const float*)d_in[1];
  const float* weight   = (const float*)d_in[2];
  const float* bias     = (const float*)d_in[3];
  float* out = (float*)d_out;

  // ws: [top2 2K][cand 8K][flags 1K][vals 8K] ... pad to 64K ... [Wp 33.6 MB]
  int*   top2    = (int*)d_ws;
  int*   candIdx = (int*)((char*)d_ws + 2048);
  int*   flags   = (int*)((char*)d_ws + 2048 + 8192);
  float* vals    = (float*)((char*)d_ws + 2048 + 8192 + 1024);
  unsigned short* Wp = (unsigned short*)((char*)d_ws + 65536);
  const bool bigws = ws_size >= 65536ull + 256ull * 65536ull * 2ull;

  init_bias_k<<<dim3(1000), 256, 0, stream>>>(bias, out);
  rgemm_k<<<dim3(2, 8, 28), 256, 0, stream>>>(inputR, weight, out);
  top8_k<<<dim3(256), 64, 0, stream>>>(out, top2, candIdx, flags, out + 256000);
  rdot_k<<<dim3(256, 8), 256, 0, stream>>>(inputR, weight, bias, candIdx, flags, vals);
  select_k<<<dim3(256), 64, 0, stream>>>(vals, candIdx, flags, top2);
  if (bigws) {
    pack_k<<<dim3(256, 4), 256, 0, stream>>>(weight, top2, Wp);
    spd_k<<<dim3(1024), 256, 0, stream>>>(inputSPD, Wp, out + 256000);
  } else {
    spd_fb_k<<<dim3(1024), 256, 0, stream>>>(inputSPD, weight, top2, out + 256000);
  }
}